// Round 21
// baseline (243.615 us; speedup 1.0000x reference)
//
#include <hip/hip_runtime.h>
#include <hip/hip_bf16.h>
#include <math.h>

#define IN_CH 128
#define HID 64
#define HEADS 4
#define C1 (HEADS*HID)   // 256
#define OUT_CH 64
#define NSL 64           // edge slices for CSR build
#define MAXNH 25024      // LDS histogram capacity (>= (N+1)/2)

typedef __attribute__((ext_vector_type(8))) short short8v;
typedef __attribute__((ext_vector_type(4))) float f32x4;

__device__ __forceinline__ float lrelu(float x){ return x > 0.f ? x : 0.2f*x; }

__device__ __forceinline__ ushort f2b(float f){
  unsigned u = __builtin_bit_cast(unsigned, f);
  unsigned r = (u + 0x7FFF + ((u>>16)&1)) >> 16;
  return (ushort)r;
}
__device__ __forceinline__ float b2f(ushort b){
  unsigned u = ((unsigned)b) << 16;
  return __builtin_bit_cast(float, u);
}

__device__ __forceinline__ float wsum64(float v){
  #pragma unroll
  for (int m = 32; m >= 1; m >>= 1) v += __shfl_xor(v, m, 64);
  return v;
}

__device__ __forceinline__ float dot2(unsigned ua, unsigned ub){
  float la = __builtin_bit_cast(float, ua << 16);
  float ha = __builtin_bit_cast(float, ua & 0xFFFF0000u);
  float lb = __builtin_bit_cast(float, ub << 16);
  float hb = __builtin_bit_cast(float, ub & 0xFFFF0000u);
  return la*lb + ha*hb;
}

__device__ __forceinline__ void unpack8(uint4 u, float* v){
  v[0]=__builtin_bit_cast(float,u.x<<16); v[1]=__builtin_bit_cast(float,u.x&0xFFFF0000u);
  v[2]=__builtin_bit_cast(float,u.y<<16); v[3]=__builtin_bit_cast(float,u.y&0xFFFF0000u);
  v[4]=__builtin_bit_cast(float,u.z<<16); v[5]=__builtin_bit_cast(float,u.z&0xFFFF0000u);
  v[6]=__builtin_bit_cast(float,u.w<<16); v[7]=__builtin_bit_cast(float,u.w&0xFFFF0000u);
}

// ---------------- CSR build v2 + fused fattc ----------------
// blocks [0, 2*NSL): LDS-private histograms (no global atomics).
// blocks [2*NSL, ...): x cast + conv1 scores, 16 nodes per 1024-thr block.
__global__ __launch_bounds__(1024) void k_histfatt(
    const int* __restrict__ dst, unsigned* __restrict__ part, int e, int nh, int n,
    const float* __restrict__ x, const float* __restrict__ was4,
    const float* __restrict__ wad4, ushort* __restrict__ xb,
    float* __restrict__ as1, float* __restrict__ ad1){
  __shared__ unsigned hist[MAXNH];
  int b = blockIdx.x;
  int tid = threadIdx.x;
  if (b < 2*NSL){
    int half = b >> 6, slice = b & (NSL-1);
    int base = half*nh;
    int cnt = half ? (n - nh) : nh;
    for (int i = tid; i < cnt; i += 1024) hist[i] = 0u;
    __syncthreads();
    int ES = (e + NSL - 1) / NSL;
    int es = slice*ES, ee = min(e, es + ES);
    for (int t = es + tid; t < ee; t += 1024){
      int d = dst[t];
      if (d >= base && d < base + cnt) atomicAdd(&hist[d - base], 1u);
    }
    __syncthreads();
    unsigned* pb = part + (size_t)b*nh;
    for (int i = tid; i < cnt; i += 1024) pb[i] = hist[i];
    return;
  }
  // fattc: 16 nodes per block, wave per node, lane = 2 channels
  int i = (b - 2*NSL)*16 + (tid >> 6);
  int l = tid & 63;
  if (i >= n) return;
  float2 u = *(const float2*)(x + (size_t)i*IN_CH + 2*l);
  ushort2 o; o.x = f2b(u.x); o.y = f2b(u.y);
  *(ushort2*)(xb + (size_t)i*IN_CH + 2*l) = o;
  float v0 = u.x, v1 = u.y;
  f32x4 s0 = *(const f32x4*)(was4 + 8*l);
  f32x4 s1 = *(const f32x4*)(was4 + 8*l + 4);
  f32x4 d0 = *(const f32x4*)(wad4 + 8*l);
  f32x4 d1 = *(const f32x4*)(wad4 + 8*l + 4);
  f32x4 ps, pd;
  #pragma unroll
  for (int h = 0; h < 4; ++h){
    ps[h] = wsum64(v0*s0[h] + v1*s1[h]);
    pd[h] = wsum64(v0*d0[h] + v1*d1[h]);
  }
  if (l == 0){
    *(f32x4*)(as1 + 4*i) = ps;
    *(f32x4*)(ad1 + 4*i) = pd;
  }
}

// deg = 1 + sum over slices (running prefix, O(1) regs); also block-reduce -> bsum.
__global__ void k_degred(unsigned* __restrict__ part, int* __restrict__ deg,
                         int* __restrict__ bsum, int n, int nh){
  __shared__ int buf[256];
  int b = blockIdx.x, tid = threadIdx.x;
  int g = b*256 + tid;
  int dv = 0;
  if (g < n){
    int half = (g >= nh) ? 1 : 0;
    int i = g - half*nh;
    size_t base = (size_t)(half*NSL)*nh + i;
    unsigned run = 0;
    #pragma unroll 8
    for (int s = 0; s < NSL; ++s){
      unsigned v = part[base + (size_t)s*nh];
      part[base + (size_t)s*nh] = run;
      run += v;
    }
    dv = (int)run + 1;               // +1 self-loop
    deg[g] = dv;
  }
  buf[tid] = dv;
  __syncthreads();
  for (int off = 128; off > 0; off >>= 1){
    if (tid < off) buf[tid] += buf[tid + off];
    __syncthreads();
  }
  if (tid == 0) bsum[b] = buf[0];
}

__global__ void k_scanb(int* bsum, int nb){
  __shared__ int buf[256];
  int tid = threadIdx.x;
  int v = (tid < nb) ? bsum[tid] : 0;
  buf[tid] = v;
  __syncthreads();
  for (int off = 1; off < 256; off <<= 1){
    int t = (tid >= off) ? buf[tid - off] : 0;
    __syncthreads();
    buf[tid] += t;
    __syncthreads();
  }
  if (tid < nb) bsum[tid] = buf[tid] - v;
}

// rowptr + self-loop slot
__global__ void k_scanfinal(const int* __restrict__ deg, const int* __restrict__ bsum,
                            int* rowptr, ushort* csrc, int n){
  __shared__ int buf[256];
  int b = blockIdx.x, tid = threadIdx.x;
  int i = b*256 + tid;
  int v = (i < n) ? deg[i] : 0;
  buf[tid] = v;
  __syncthreads();
  for (int off = 1; off < 256; off <<= 1){
    int t = (tid >= off) ? buf[tid - off] : 0;
    __syncthreads();
    buf[tid] += t;
    __syncthreads();
  }
  if (i < n){
    int r = bsum[b] + buf[tid];       // rowptr[i+1]
    rowptr[i + 1] = r;
    csrc[r - 1] = (ushort)i;          // self-loop in last slot
  }
  if (b == 0 && tid == 0) rowptr[0] = 0;
}

// 128 blocks; LDS cursors seeded from rowptr + slice-prefix; LDS atomics only.
__global__ __launch_bounds__(1024) void k_scatter2(
    const int* __restrict__ src, const int* __restrict__ dst,
    const int* __restrict__ rowptr, const unsigned* __restrict__ part,
    ushort* __restrict__ csrc, int e, int nh, int n){
  __shared__ unsigned cur[MAXNH];
  int b = blockIdx.x;
  int half = b >> 6, slice = b & (NSL-1);
  int base = half*nh;
  int cnt = half ? (n - nh) : nh;
  int tid = threadIdx.x;
  const unsigned* pb = part + (size_t)b*nh;
  for (int i = tid; i < cnt; i += 1024)
    cur[i] = (unsigned)rowptr[base + i] + pb[i];
  __syncthreads();
  int ES = (e + NSL - 1) / NSL;
  int es = slice*ES, ee = min(e, es + ES);
  for (int t = es + tid; t < ee; t += 1024){
    int d = dst[t];
    if (d >= base && d < base + cnt){
      unsigned slot = atomicAdd(&cur[d - base], 1u);
      __builtin_nontemporal_store((ushort)src[t], csrc + slot);
    }
  }
}

// ---------------- fused setup: W transposes + folds ----------------
__global__ void k_setup(const float* __restrict__ W1, ushort* __restrict__ W1t,
                        const float* __restrict__ W2, ushort* __restrict__ W2t,
                        const float* __restrict__ as1v, const float* __restrict__ ad1v,
                        const float* __restrict__ as2v, const float* __restrict__ ad2v,
                        float* was4, float* wad4, float* w2s, float* w2d){
  int b = blockIdx.x, tid = threadIdx.x;
  if (b < 128){
    int i = b*256 + tid;                  // over IN_CH*C1 = 32768
    int k = i >> 8, c = i & 255;
    W1t[(size_t)c*IN_CH + k] = f2b(W1[i]);
  } else if (b < 192){
    int i = (b - 128)*256 + tid;          // over C1*OUT_CH = 16384
    int k = i >> 6, c = i & 63;
    W2t[(size_t)c*C1 + k] = f2b(W2[i]);
  } else if (b == 192){
    #pragma unroll
    for (int r = 0; r < 2; ++r){
      int t = tid + r*256;
      int c = t >> 2, h = t & 3;
      float s = 0.f, d = 0.f;
      for (int j = 0; j < HID; ++j){
        float w = W1[c*C1 + h*HID + j];
        s += w * as1v[h*HID + j];
        d += w * ad1v[h*HID + j];
      }
      was4[t] = s; wad4[t] = d;
    }
  } else {
    float s = 0.f, d = 0.f;
    for (int o = 0; o < OUT_CH; ++o){
      float w = W2[tid*OUT_CH + o];
      s += w * as2v[o];
      d += w * ad2v[o];
    }
    w2s[tid] = s; w2d[tid] = d;
  }
}

// as2/ad2 from z1: 4 nodes/block, wave per node, lane = 4 channels
__global__ __launch_bounds__(256) void k_fatt2(const ushort* __restrict__ z1b,
    const float* __restrict__ w2s, const float* __restrict__ w2d,
    float* __restrict__ as2, float* __restrict__ ad2, int n){
  int i = blockIdx.x*4 + (threadIdx.x >> 6);
  int l = threadIdx.x & 63;
  if (i >= n) return;
  ushort4 u = *(const ushort4*)(z1b + (size_t)i*C1 + 4*l);
  float v0 = b2f(u.x), v1 = b2f(u.y), v2 = b2f(u.z), v3 = b2f(u.w);
  f32x4 s = *(const f32x4*)(w2s + 4*l);
  f32x4 d = *(const f32x4*)(w2d + 4*l);
  float ps = wsum64(v0*s[0] + v1*s[1] + v2*s[2] + v3*s[3]);
  float pd = wsum64(v0*d[0] + v1*d[1] + v2*d[2] + v3*d[3]);
  if (l == 0){ as2[i] = ps; ad2[i] = pd; }
}

// ---------------- conv1 fused softmax+aggregate: 16 lanes/node, 4 nodes/block --
__global__ __launch_bounds__(64) void k_fagg1(
    const ushort* __restrict__ xb, const float* __restrict__ as1,
    const float* __restrict__ ad1, const int* __restrict__ rowptr,
    const ushort* __restrict__ csrc, ushort* __restrict__ xagg, int n)
{
  __shared__ float  s_w[4][4][17];
  __shared__ ushort s_src[4][16];
  int tid = threadIdx.x;
  int grp = tid >> 4, ln = tid & 15;
  int i = blockIdx.x*4 + grp;
  if (i >= n) return;               // group-local LDS, wave-synchronous: safe
  int beg = rowptr[i], end = rowptr[i+1];
  f32x4 ad4 = *(const f32x4*)(ad1 + 4*i);

  // pass A: sum of exp(alpha); cache (sj, exp) for chunks 0,1
  f32x4 S = (f32x4)(0.f);
  f32x4 ev0 = (f32x4)(0.f), ev1 = (f32x4)(0.f);
  int sj0 = 0, sj1 = 0, it = 0;
  for (int sl = beg + ln; sl < end; sl += 16, ++it){
    int sj = csrc[sl];
    f32x4 a4 = *(const f32x4*)(as1 + 4*sj);
    f32x4 ev;
    #pragma unroll
    for (int h = 0; h < 4; ++h)
      ev[h] = __expf(fminf(lrelu(a4[h] + ad4[h]), 60.f));
    if (it == 0){ ev0 = ev; sj0 = sj; }
    else if (it == 1){ ev1 = ev; sj1 = sj; }
    #pragma unroll
    for (int h = 0; h < 4; ++h) S[h] += ev[h];
  }
  f32x4 rd;
  #pragma unroll
  for (int h = 0; h < 4; ++h){
    float sh = S[h];
    #pragma unroll
    for (int k = 8; k >= 1; k >>= 1) sh += __shfl_xor(sh, k, 16);
    rd[h] = 1.f/(sh + 1e-16f);
  }

  // pass B: 4-deep gather pipeline
  float acc[4][8] = {};
  int nch = (end - beg + 15) >> 4;
  for (int c = 0; c < nch; ++c){
    int cs = beg + c*16;
    int cn = min(16, end - cs);
    if (ln < cn){
      int sj; f32x4 ev;
      if (c == 0){ sj = sj0; ev = ev0; }
      else if (c == 1){ sj = sj1; ev = ev1; }
      else {
        sj = csrc[cs + ln];
        f32x4 a4 = *(const f32x4*)(as1 + 4*sj);
        #pragma unroll
        for (int h = 0; h < 4; ++h)
          ev[h] = __expf(fminf(lrelu(a4[h] + ad4[h]), 60.f));
      }
      s_src[grp][ln] = (ushort)sj;
      #pragma unroll
      for (int h = 0; h < 4; ++h)
        s_w[grp][h][ln] = ev[h] * rd[h];
    }
    int e = 0;
    if (cn >= 4){
      uint4 u0 = *(const uint4*)(xb + (size_t)s_src[grp][0]*IN_CH + ln*8);
      uint4 u1 = *(const uint4*)(xb + (size_t)s_src[grp][1]*IN_CH + ln*8);
      uint4 u2 = *(const uint4*)(xb + (size_t)s_src[grp][2]*IN_CH + ln*8);
      uint4 u3 = *(const uint4*)(xb + (size_t)s_src[grp][3]*IN_CH + ln*8);
      for (; e + 7 < cn; e += 4){
        uint4 n0 = *(const uint4*)(xb + (size_t)s_src[grp][e+4]*IN_CH + ln*8);
        uint4 n1 = *(const uint4*)(xb + (size_t)s_src[grp][e+5]*IN_CH + ln*8);
        uint4 n2 = *(const uint4*)(xb + (size_t)s_src[grp][e+6]*IN_CH + ln*8);
        uint4 n3 = *(const uint4*)(xb + (size_t)s_src[grp][e+7]*IN_CH + ln*8);
        float v0[8], v1[8], v2[8], v3[8];
        unpack8(u0, v0); unpack8(u1, v1); unpack8(u2, v2); unpack8(u3, v3);
        #pragma unroll
        for (int h = 0; h < 4; ++h){
          float w0 = s_w[grp][h][e],   w1 = s_w[grp][h][e+1];
          float w2 = s_w[grp][h][e+2], w3 = s_w[grp][h][e+3];
          #pragma unroll
          for (int cc = 0; cc < 8; ++cc)
            acc[h][cc] += w0*v0[cc] + w1*v1[cc] + w2*v2[cc] + w3*v3[cc];
        }
        u0 = n0; u1 = n1; u2 = n2; u3 = n3;
      }
      {
        float v0[8], v1[8], v2[8], v3[8];
        unpack8(u0, v0); unpack8(u1, v1); unpack8(u2, v2); unpack8(u3, v3);
        #pragma unroll
        for (int h = 0; h < 4; ++h){
          float w0 = s_w[grp][h][e],   w1 = s_w[grp][h][e+1];
          float w2 = s_w[grp][h][e+2], w3 = s_w[grp][h][e+3];
          #pragma unroll
          for (int cc = 0; cc < 8; ++cc)
            acc[h][cc] += w0*v0[cc] + w1*v1[cc] + w2*v2[cc] + w3*v3[cc];
        }
        e += 4;
      }
    }
    for (; e < cn; ++e){
      uint4 u = *(const uint4*)(xb + (size_t)s_src[grp][e]*IN_CH + ln*8);
      float v[8];
      unpack8(u, v);
      #pragma unroll
      for (int h = 0; h < 4; ++h){
        float w = s_w[grp][h][e];
        #pragma unroll
        for (int cc = 0; cc < 8; ++cc) acc[h][cc] += w*v[cc];
      }
    }
  }
  #pragma unroll
  for (int h = 0; h < 4; ++h){
    uint4 o;
    o.x = (unsigned)f2b(acc[h][0]) | ((unsigned)f2b(acc[h][1])<<16);
    o.y = (unsigned)f2b(acc[h][2]) | ((unsigned)f2b(acc[h][3])<<16);
    o.z = (unsigned)f2b(acc[h][4]) | ((unsigned)f2b(acc[h][5])<<16);
    o.w = (unsigned)f2b(acc[h][6]) | ((unsigned)f2b(acc[h][7])<<16);
    *(uint4*)(xagg + (size_t)i*512 + h*128 + ln*8) = o;
  }
}

// ---------------- conv2 fused softmax+aggregate: 16 lanes/node, 4 nodes/block --
__global__ __launch_bounds__(64) void k_fagg2(
    const ushort* __restrict__ h2b, const float* __restrict__ as2,
    const float* __restrict__ ad2, const int* __restrict__ rowptr,
    const ushort* __restrict__ csrc, const float* __restrict__ bias,
    ushort* __restrict__ z2b, int n)
{
  __shared__ float  s_w[4][17];
  __shared__ ushort s_src[4][16];
  int tid = threadIdx.x;
  int grp = tid >> 4, ln = tid & 15;
  int i = blockIdx.x*4 + grp;
  if (i >= n) return;
  int beg = rowptr[i], end = rowptr[i+1];
  float adv = ad2[i];

  float S = 0.f;
  float ev0 = 0.f, ev1 = 0.f;
  int sj0 = 0, sj1 = 0, it = 0;
  for (int sl = beg + ln; sl < end; sl += 16, ++it){
    int sj = csrc[sl];
    float ev = __expf(fminf(lrelu(as2[sj] + adv), 60.f));
    if (it == 0){ ev0 = ev; sj0 = sj; }
    else if (it == 1){ ev1 = ev; sj1 = sj; }
    S += ev;
  }
  #pragma unroll
  for (int k = 8; k >= 1; k >>= 1) S += __shfl_xor(S, k, 16);
  float rd = 1.f/(S + 1e-16f);

  float acc[4] = {};
  int nch = (end - beg + 15) >> 4;
  for (int c = 0; c < nch; ++c){
    int cs = beg + c*16;
    int cn = min(16, end - cs);
    if (ln < cn){
      int sj; float ev;
      if (c == 0){ sj = sj0; ev = ev0; }
      else if (c == 1){ sj = sj1; ev = ev1; }
      else { sj = csrc[cs + ln]; ev = __expf(fminf(lrelu(as2[sj] + adv), 60.f)); }
      s_src[grp][ln] = (ushort)sj;
      s_w[grp][ln] = ev * rd;
    }
    int e = 0;
    for (; e + 1 < cn; e += 2){
      int sjA = s_src[grp][e], sjB = s_src[grp][e+1];
      float wA = s_w[grp][e], wB = s_w[grp][e+1];
      ushort4 uA = *(const ushort4*)(h2b + (size_t)sjA*OUT_CH + ln*4);
      ushort4 uB = *(const ushort4*)(h2b + (size_t)sjB*OUT_CH + ln*4);
      acc[0] += wA*b2f(uA.x) + wB*b2f(uB.x);
      acc[1] += wA*b2f(uA.y) + wB*b2f(uB.y);
      acc[2] += wA*b2f(uA.z) + wB*b2f(uB.z);
      acc[3] += wA*b2f(uA.w) + wB*b2f(uB.w);
    }
    if (e < cn){
      int sj = s_src[grp][e];
      float w = s_w[grp][e];
      ushort4 u = *(const ushort4*)(h2b + (size_t)sj*OUT_CH + ln*4);
      acc[0] += w*b2f(u.x); acc[1] += w*b2f(u.y);
      acc[2] += w*b2f(u.z); acc[3] += w*b2f(u.w);
    }
  }
  ushort4 o;
  o.x = f2b(acc[0] + bias[ln*4]);
  o.y = f2b(acc[1] + bias[ln*4+1]);
  o.z = f2b(acc[2] + bias[ln*4+2]);
  o.w = f2b(acc[3] + bias[ln*4+3]);
  *(ushort4*)(z2b + (size_t)i*OUT_CH + ln*4) = o;
}

// ---------------- bf16 MFMA GEMM, BM=128, BN=64, BK=64, strided, batched-z ----
template<bool RELU_BIAS>
__global__ __launch_bounds__(256) void k_gemm2(
    const ushort* __restrict__ A, const ushort* __restrict__ Bt,
    ushort* __restrict__ Cb, const float* __restrict__ bias,
    int M, int K, int lda, int ldc, int aZ, int bZ, int cZ)
{
  constexpr int BM = 128, BN = 64, NF = 2;
  __shared__ uint4 As[BM*8];
  __shared__ uint4 Bs[BN*8];
  int tid = threadIdx.x;
  int wave = tid >> 6, lane = tid & 63;
  int wr = wave >> 1, wc = wave & 1;
  int bm = blockIdx.y * BM;
  int z = blockIdx.z;
  const ushort* Az = A + (size_t)z*aZ;
  const ushort* Bz = Bt + (size_t)z*bZ;
  int g = lane >> 4, lr = lane & 15;

  f32x4 acc[4][NF];
  #pragma unroll
  for (int m = 0; m < 4; ++m)
    #pragma unroll
    for (int n = 0; n < NF; ++n) acc[m][n] = (f32x4)(0.f);

  for (int k0 = 0; k0 < K; k0 += 64){
    for (int idx = tid; idx < BM*8; idx += 256){
      int r = idx >> 3, c = idx & 7;
      int gr = bm + r;
      uint4 v = make_uint4(0u,0u,0u,0u);
      if (gr < M) v = *(const uint4*)(Az + (size_t)gr*lda + k0 + c*8);
      As[r*8 + (c ^ (r & 7))] = v;
    }
    for (int idx = tid; idx < BN*8; idx += 256){
      int r = idx >> 3, c = idx & 7;
      uint4 v = *(const uint4*)(Bz + (size_t)r*K + k0 + c*8);
      Bs[r*8 + (c ^ (r & 7))] = v;
    }
    __syncthreads();
    #pragma unroll
    for (int kk = 0; kk < 2; ++kk){
      short8v af[4], bf[NF];
      #pragma unroll
      for (int m = 0; m < 4; ++m){
        int r = wr*64 + m*16 + lr;
        int c = kk*4 + g;
        af[m] = *(const short8v*)&As[r*8 + (c ^ (r & 7))];
      }
      #pragma unroll
      for (int n = 0; n < NF; ++n){
        int r = wc*32 + n*16 + lr;
        int c = kk*4 + g;
        bf[n] = *(const short8v*)&Bs[r*8 + (c ^ (r & 7))];
      }
      #pragma unroll
      for (int m = 0; m < 4; ++m)
        #pragma unroll
        for (int n = 0; n < NF; ++n)
          acc[m][n] = __builtin_amdgcn_mfma_f32_16x16x32_bf16(af[m], bf[n], acc[m][n], 0, 0, 0);
    }
    __syncthreads();
  }
  #pragma unroll
  for (int m = 0; m < 4; ++m){
    #pragma unroll
    for (int q = 0; q < 4; ++q){
      int row = bm + wr*64 + m*16 + g*4 + q;
      if (row < M){
        #pragma unroll
        for (int n = 0; n < NF; ++n){
          int col = wc*32 + n*16 + lr;
          float v = acc[m][n][q];
          if (RELU_BIAS) v = fmaxf(v + bias[cZ*z + col], 0.f);
          Cb[(size_t)row*ldc + cZ*z + col] = f2b(v);
        }
      }
    }
  }
}

// ---------------- decoder: 4 edges per 8-lane group (pos/neg x k, k+E/2) ------
__global__ void k_decode(const ushort* __restrict__ z2b, const int* __restrict__ pos,
                         const int* __restrict__ neg, float* __restrict__ out, int e){
  int g = blockIdx.x*256 + threadIdx.x;
  int hf = e >> 1;
  int k = g >> 3;
  int sub = g & 7;
  if (k >= hf) return;
  int a0 = __builtin_nontemporal_load(pos + k);
  int b0 = __builtin_nontemporal_load(pos + e + k);
  int a1 = __builtin_nontemporal_load(pos + k + hf);
  int b1 = __builtin_nontemporal_load(pos + e + k + hf);
  int a2 = __builtin_nontemporal_load(neg + k);
  int b2 = __builtin_nontemporal_load(neg + e + k);
  int a3 = __builtin_nontemporal_load(neg + k + hf);
  int b3 = __builtin_nontemporal_load(neg + e + k + hf);
  uint4 ua0 = *(const uint4*)(z2b + (size_t)a0*OUT_CH + sub*8);
  uint4 ub0 = *(const uint4*)(z2b + (size_t)b0*OUT_CH + sub*8);
  uint4 ua1 = *(const uint4*)(z2b + (size_t)a1*OUT_CH + sub*8);
  uint4 ub1 = *(const uint4*)(z2b + (size_t)b1*OUT_CH + sub*8);
  uint4 ua2 = *(const uint4*)(z2b + (size_t)a2*OUT_CH + sub*8);
  uint4 ub2 = *(const uint4*)(z2b + (size_t)b2*OUT_CH + sub*8);
  uint4 ua3 = *(const uint4*)(z2b + (size_t)a3*OUT_CH + sub*8);
  uint4 ub3 = *(const uint4*)(z2b + (size_t)b3*OUT_CH + sub*8);
  float p0 = dot2(ua0.x, ub0.x) + dot2(ua0.y, ub0.y) + dot2(ua0.z, ub0.z) + dot2(ua0.w, ub0.w);
  float p1 = dot2(ua1.x, ub1.x) + dot2(ua1.y, ub1.y) + dot2(ua1.z, ub1.z) + dot2(ua1.w, ub1.w);
  float p2 = dot2(ua2.x, ub2.x) + dot2(ua2.y, ub2.y) + dot2(ua2.z, ub2.z) + dot2(ua2.w, ub2.w);
  float p3 = dot2(ua3.x, ub3.x) + dot2(ua3.y, ub3.y) + dot2(ua3.z, ub3.z) + dot2(ua3.w, ub3.w);
  #pragma unroll
  for (int mm = 4; mm >= 1; mm >>= 1){
    p0 += __shfl_xor(p0, mm, 64);
    p1 += __shfl_xor(p1, mm, 64);
    p2 += __shfl_xor(p2, mm, 64);
    p3 += __shfl_xor(p3, mm, 64);
  }
  if (sub == 0){
    __builtin_nontemporal_store(p0, out + k);
    __builtin_nontemporal_store(p1, out + k + hf);
    __builtin_nontemporal_store(p2, out + e + k);
    __builtin_nontemporal_store(p3, out + e + k + hf);
  }
}

extern "C" void kernel_launch(void* const* d_in, const int* in_sizes, int n_in,
                              void* d_out, int out_size, void* d_ws, size_t ws_size,
                              hipStream_t stream) {
  const float* x        = (const float*)d_in[0];
  const int*   pos      = (const int*)d_in[1];
  const int*   neg      = (const int*)d_in[2];
  const float* W1       = (const float*)d_in[3];
  const float* att_src1 = (const float*)d_in[4];
  const float* att_dst1 = (const float*)d_in[5];
  const float* b1       = (const float*)d_in[6];
  const float* W2       = (const float*)d_in[7];
  const float* att_src2 = (const float*)d_in[8];
  const float* att_dst2 = (const float*)d_in[9];
  const float* b2       = (const float*)d_in[10];
  float* out = (float*)d_out;

  const int N = in_sizes[0] / IN_CH;   // 50000
  const int E = in_sizes[1] / 2;       // 800000
  const int NNZ = E + N;               // edges + self-loops
  const int NH = (N + 1) / 2;          // 25000 (<= MAXNH)

  char* w = (char*)d_ws;
  ushort* xb   = (ushort*)w;  w += (size_t)N*IN_CH*2;
  ushort* xagg = (ushort*)w;  w += (size_t)N*512*2;          // 51.2MB; sub-reused below
  ushort* z1b  = (ushort*)w;  w += (size_t)N*C1*2;
  float* as1   = (float*)w;   w += (size_t)N*4*4;
  float* ad1   = (float*)w;   w += (size_t)N*4*4;
  float* as2   = (float*)w;   w += (size_t)N*4;
  float* ad2   = (float*)w;   w += (size_t)N*4;
  ushort* W1t  = (ushort*)w;  w += (size_t)C1*IN_CH*2;
  ushort* W2t  = (ushort*)w;  w += (size_t)OUT_CH*C1*2;
  float* was4  = (float*)w;   w += 512*4;
  float* wad4  = (float*)w;   w += 512*4;
  float* w2s   = (float*)w;   w += 256*4;
  float* w2d   = (float*)w;   w += 256*4;
  int* deg     = (int*)w;     w += (size_t)N*4;
  int* rowptr  = (int*)w;     w += (size_t)(N+1)*4;
  int* bsum    = (int*)w;     w += (size_t)256*4;
  unsigned* part = (unsigned*)w; w += (size_t)2*NSL*NH*4;    // 12.8MB
  ushort* csrc = (ushort*)w;  w += (size_t)NNZ*2;

  // sub-allocations inside xagg (region dead after z1 GEMM):
  ushort* h2b = xagg;                                  // 6.4MB
  ushort* z2b = xagg + (size_t)N*OUT_CH;               // 6.4MB

  int nb = (N + 255)/256;
  int fb = (N + 15)/16;                // 3125 fattc blocks
  const int* pdst = pos + E;

  k_setup<<<194, 256, 0, stream>>>(W1, W1t, W2, W2t,
      att_src1, att_dst1, att_src2, att_dst2, was4, wad4, w2s, w2d);
  k_histfatt<<<2*NSL + fb, 1024, 0, stream>>>(pdst, part, E, NH, N,
      x, was4, wad4, xb, as1, ad1);
  k_degred<<<nb, 256, 0, stream>>>(part, deg, bsum, N, NH);
  k_scanb<<<1, 256, 0, stream>>>(bsum, nb);
  k_scanfinal<<<nb, 256, 0, stream>>>(deg, bsum, rowptr, csrc, N);
  k_scatter2<<<2*NSL, 1024, 0, stream>>>(pos, pdst, rowptr, part, csrc, E, NH, N);

  k_fagg1<<<(N + 3)/4, 64, 0, stream>>>(xb, as1, ad1, rowptr, csrc, xagg, N);

  {  // z1 = relu(blockdiag(xagg_h @ W1_h) + b1), 4 heads via blockIdx.z
    dim3 g(1, (N + 127)/128, 4);
    k_gemm2<true><<<g, 256, 0, stream>>>(xagg, W1t, z1b, b1,
        N, IN_CH, 512, C1, IN_CH, OUT_CH*IN_CH, OUT_CH);
  }
  k_fatt2<<<(N + 3)/4, 256, 0, stream>>>(z1b, w2s, w2d, as2, ad2, N);

  {  // h2 = z1 @ W2
    dim3 g(1, (N + 127)/128, 1);
    k_gemm2<false><<<g, 256, 0, stream>>>(z1b, W2t, h2b, nullptr,
        N, C1, C1, OUT_CH, 0, 0, 0);
  }
  k_fagg2<<<(N + 3)/4, 64, 0, stream>>>(h2b, as2, ad2, rowptr, csrc, b2, z2b, N);

  int db = (int)(((size_t)(E/2)*8 + 255)/256);
  k_decode<<<db, 256, 0, stream>>>(z2b, pos, neg, out, E);
}

// Round 22
// 240.026 us; speedup vs baseline: 1.0150x; 1.0150x over previous
//
#include <hip/hip_runtime.h>
#include <hip/hip_bf16.h>
#include <math.h>

#define IN_CH 128
#define HID 64
#define HEADS 4
#define C1 (HEADS*HID)   // 256
#define OUT_CH 64
#define NSL 64           // edge slices for CSR build
#define NQ 4             // node quarters
#define MAXNQ 12512      // LDS capacity per quarter (>= ceil(N/4))

typedef __attribute__((ext_vector_type(8))) short short8v;
typedef __attribute__((ext_vector_type(4))) float f32x4;

__device__ __forceinline__ float lrelu(float x){ return x > 0.f ? x : 0.2f*x; }

__device__ __forceinline__ ushort f2b(float f){
  unsigned u = __builtin_bit_cast(unsigned, f);
  unsigned r = (u + 0x7FFF + ((u>>16)&1)) >> 16;
  return (ushort)r;
}
__device__ __forceinline__ float b2f(ushort b){
  unsigned u = ((unsigned)b) << 16;
  return __builtin_bit_cast(float, u);
}

__device__ __forceinline__ float wsum64(float v){
  #pragma unroll
  for (int m = 32; m >= 1; m >>= 1) v += __shfl_xor(v, m, 64);
  return v;
}

__device__ __forceinline__ float dot2(unsigned ua, unsigned ub){
  float la = __builtin_bit_cast(float, ua << 16);
  float ha = __builtin_bit_cast(float, ua & 0xFFFF0000u);
  float lb = __builtin_bit_cast(float, ub << 16);
  float hb = __builtin_bit_cast(float, ub & 0xFFFF0000u);
  return la*lb + ha*hb;
}

__device__ __forceinline__ void unpack8(uint4 u, float* v){
  v[0]=__builtin_bit_cast(float,u.x<<16); v[1]=__builtin_bit_cast(float,u.x&0xFFFF0000u);
  v[2]=__builtin_bit_cast(float,u.y<<16); v[3]=__builtin_bit_cast(float,u.y&0xFFFF0000u);
  v[4]=__builtin_bit_cast(float,u.z<<16); v[5]=__builtin_bit_cast(float,u.z&0xFFFF0000u);
  v[6]=__builtin_bit_cast(float,u.w<<16); v[7]=__builtin_bit_cast(float,u.w&0xFFFF0000u);
}

// ---------------- CSR build v3: 4 node-quarters x 64 slices, 50KB LDS ---------

// 256 blocks. LDS histogram per (quarter, slice); coalesced dump to part.
__global__ __launch_bounds__(1024) void k_hist2(
    const int* __restrict__ dst, unsigned* __restrict__ part, int e, int nq, int n){
  __shared__ unsigned hist[MAXNQ];
  int b = blockIdx.x;
  int q = b >> 6, slice = b & (NSL-1);
  int base = q*nq;
  int cnt = min(nq, n - base);
  int tid = threadIdx.x;
  for (int i = tid; i < cnt; i += 1024) hist[i] = 0u;
  __syncthreads();
  int ES = (e + NSL - 1) / NSL;
  int es = slice*ES, ee = min(e, es + ES);
  for (int t = es + tid; t < ee; t += 1024){
    int d = dst[t];
    if (d >= base && d < base + cnt) atomicAdd(&hist[d - base], 1u);
  }
  __syncthreads();
  unsigned* pb = part + (size_t)b*nq;
  for (int i = tid; i < cnt; i += 1024) pb[i] = hist[i];
}

// deg = 1 + sum over slices (running prefix, O(1) regs); block-reduce -> bsum.
__global__ void k_degred(unsigned* __restrict__ part, int* __restrict__ deg,
                         int* __restrict__ bsum, int n, int nq){
  __shared__ int buf[256];
  int b = blockIdx.x, tid = threadIdx.x;
  int g = b*256 + tid;
  int dv = 0;
  if (g < n){
    int q = g / nq;
    int i = g - q*nq;
    size_t base = (size_t)(q*NSL)*nq + i;
    unsigned run = 0;
    #pragma unroll 8
    for (int s = 0; s < NSL; ++s){
      unsigned v = part[base + (size_t)s*nq];
      part[base + (size_t)s*nq] = run;
      run += v;
    }
    dv = (int)run + 1;               // +1 self-loop
    deg[g] = dv;
  }
  buf[tid] = dv;
  __syncthreads();
  for (int off = 128; off > 0; off >>= 1){
    if (tid < off) buf[tid] += buf[tid + off];
    __syncthreads();
  }
  if (tid == 0) bsum[b] = buf[0];
}

// rowptr + self-loop slot; per-block bsum prefix computed inline (no scanb pass)
__global__ void k_scanfinal(const int* __restrict__ deg, const int* __restrict__ bsum,
                            int* rowptr, ushort* csrc, int n){
  __shared__ int buf[256];
  __shared__ int s_base;
  int b = blockIdx.x, tid = threadIdx.x;
  // prefix of bsum[0..b)
  int part = 0;
  for (int s = tid; s < b; s += 256) part += bsum[s];
  buf[tid] = part;
  __syncthreads();
  for (int off = 128; off > 0; off >>= 1){
    if (tid < off) buf[tid] += buf[tid + off];
    __syncthreads();
  }
  if (tid == 0) s_base = buf[0];
  __syncthreads();
  int base = s_base;

  int i = b*256 + tid;
  int v = (i < n) ? deg[i] : 0;
  buf[tid] = v;
  __syncthreads();
  for (int off = 1; off < 256; off <<= 1){
    int t = (tid >= off) ? buf[tid - off] : 0;
    __syncthreads();
    buf[tid] += t;
    __syncthreads();
  }
  if (i < n){
    int r = base + buf[tid];          // rowptr[i+1]
    rowptr[i + 1] = r;
    csrc[r - 1] = (ushort)i;          // self-loop in last slot
  }
  if (b == 0 && tid == 0) rowptr[0] = 0;
}

// 256 blocks; LDS cursors seeded from rowptr + slice-prefix; LDS atomics only.
__global__ __launch_bounds__(1024) void k_scatter2(
    const int* __restrict__ src, const int* __restrict__ dst,
    const int* __restrict__ rowptr, const unsigned* __restrict__ part,
    ushort* __restrict__ csrc, int e, int nq, int n){
  __shared__ unsigned cur[MAXNQ];
  int b = blockIdx.x;
  int q = b >> 6, slice = b & (NSL-1);
  int base = q*nq;
  int cnt = min(nq, n - base);
  int tid = threadIdx.x;
  const unsigned* pb = part + (size_t)b*nq;
  for (int i = tid; i < cnt; i += 1024)
    cur[i] = (unsigned)rowptr[base + i] + pb[i];
  __syncthreads();
  int ES = (e + NSL - 1) / NSL;
  int es = slice*ES, ee = min(e, es + ES);
  for (int t = es + tid; t < ee; t += 1024){
    int d = dst[t];
    if (d >= base && d < base + cnt){
      unsigned slot = atomicAdd(&cur[d - base], 1u);
      __builtin_nontemporal_store((ushort)src[t], csrc + slot);
    }
  }
}

// ---------------- fused setup: W transposes + folds ----------------
__global__ void k_setup(const float* __restrict__ W1, ushort* __restrict__ W1t,
                        const float* __restrict__ W2, ushort* __restrict__ W2t,
                        const float* __restrict__ as1v, const float* __restrict__ ad1v,
                        const float* __restrict__ as2v, const float* __restrict__ ad2v,
                        float* was4, float* wad4, float* w2s, float* w2d){
  int b = blockIdx.x, tid = threadIdx.x;
  if (b < 128){
    int i = b*256 + tid;                  // over IN_CH*C1 = 32768
    int k = i >> 8, c = i & 255;
    W1t[(size_t)c*IN_CH + k] = f2b(W1[i]);
  } else if (b < 192){
    int i = (b - 128)*256 + tid;          // over C1*OUT_CH = 16384
    int k = i >> 6, c = i & 63;
    W2t[(size_t)c*C1 + k] = f2b(W2[i]);
  } else if (b == 192){
    #pragma unroll
    for (int r = 0; r < 2; ++r){
      int t = tid + r*256;
      int c = t >> 2, h = t & 3;
      float s = 0.f, d = 0.f;
      for (int j = 0; j < HID; ++j){
        float w = W1[c*C1 + h*HID + j];
        s += w * as1v[h*HID + j];
        d += w * ad1v[h*HID + j];
      }
      was4[t] = s; wad4[t] = d;
    }
  } else {
    float s = 0.f, d = 0.f;
    for (int o = 0; o < OUT_CH; ++o){
      float w = W2[tid*OUT_CH + o];
      s += w * as2v[o];
      d += w * ad2v[o];
    }
    w2s[tid] = s; w2d[tid] = d;
  }
}

// fused: cast x->bf16 + conv1 attention scores. 4 nodes/block, wave per node.
__global__ __launch_bounds__(256) void k_fattc(const float* __restrict__ x,
    const float* __restrict__ was4, const float* __restrict__ wad4,
    ushort* __restrict__ xb, float* __restrict__ as1, float* __restrict__ ad1, int n){
  int i = blockIdx.x*4 + (threadIdx.x >> 6);
  int l = threadIdx.x & 63;
  if (i >= n) return;
  float2 u = *(const float2*)(x + (size_t)i*IN_CH + 2*l);
  ushort2 o; o.x = f2b(u.x); o.y = f2b(u.y);
  *(ushort2*)(xb + (size_t)i*IN_CH + 2*l) = o;
  float v0 = u.x, v1 = u.y;
  f32x4 s0 = *(const f32x4*)(was4 + 8*l);
  f32x4 s1 = *(const f32x4*)(was4 + 8*l + 4);
  f32x4 d0 = *(const f32x4*)(wad4 + 8*l);
  f32x4 d1 = *(const f32x4*)(wad4 + 8*l + 4);
  f32x4 ps, pd;
  #pragma unroll
  for (int h = 0; h < 4; ++h){
    ps[h] = wsum64(v0*s0[h] + v1*s1[h]);
    pd[h] = wsum64(v0*d0[h] + v1*d1[h]);
  }
  if (l == 0){
    *(f32x4*)(as1 + 4*i) = ps;
    *(f32x4*)(ad1 + 4*i) = pd;
  }
}

// as2/ad2 from z1: 4 nodes/block, wave per node, lane = 4 channels
__global__ __launch_bounds__(256) void k_fatt2(const ushort* __restrict__ z1b,
    const float* __restrict__ w2s, const float* __restrict__ w2d,
    float* __restrict__ as2, float* __restrict__ ad2, int n){
  int i = blockIdx.x*4 + (threadIdx.x >> 6);
  int l = threadIdx.x & 63;
  if (i >= n) return;
  ushort4 u = *(const ushort4*)(z1b + (size_t)i*C1 + 4*l);
  float v0 = b2f(u.x), v1 = b2f(u.y), v2 = b2f(u.z), v3 = b2f(u.w);
  f32x4 s = *(const f32x4*)(w2s + 4*l);
  f32x4 d = *(const f32x4*)(w2d + 4*l);
  float ps = wsum64(v0*s[0] + v1*s[1] + v2*s[2] + v3*s[3]);
  float pd = wsum64(v0*d[0] + v1*d[1] + v2*d[2] + v3*d[3]);
  if (l == 0){ as2[i] = ps; ad2[i] = pd; }
}

// ---------------- conv1 fused softmax+aggregate: 16 lanes/node, 4 nodes/block --
__global__ __launch_bounds__(64) void k_fagg1(
    const ushort* __restrict__ xb, const float* __restrict__ as1,
    const float* __restrict__ ad1, const int* __restrict__ rowptr,
    const ushort* __restrict__ csrc, ushort* __restrict__ xagg, int n)
{
  __shared__ float  s_w[4][4][17];
  __shared__ ushort s_src[4][16];
  int tid = threadIdx.x;
  int grp = tid >> 4, ln = tid & 15;
  int i = blockIdx.x*4 + grp;
  if (i >= n) return;               // group-local LDS, wave-synchronous: safe
  int beg = rowptr[i], end = rowptr[i+1];
  f32x4 ad4 = *(const f32x4*)(ad1 + 4*i);

  // pass A: sum of exp(alpha); cache (sj, exp) for chunks 0,1
  f32x4 S = (f32x4)(0.f);
  f32x4 ev0 = (f32x4)(0.f), ev1 = (f32x4)(0.f);
  int sj0 = 0, sj1 = 0, it = 0;
  for (int sl = beg + ln; sl < end; sl += 16, ++it){
    int sj = csrc[sl];
    f32x4 a4 = *(const f32x4*)(as1 + 4*sj);
    f32x4 ev;
    #pragma unroll
    for (int h = 0; h < 4; ++h)
      ev[h] = __expf(fminf(lrelu(a4[h] + ad4[h]), 60.f));
    if (it == 0){ ev0 = ev; sj0 = sj; }
    else if (it == 1){ ev1 = ev; sj1 = sj; }
    #pragma unroll
    for (int h = 0; h < 4; ++h) S[h] += ev[h];
  }
  f32x4 rd;
  #pragma unroll
  for (int h = 0; h < 4; ++h){
    float sh = S[h];
    #pragma unroll
    for (int k = 8; k >= 1; k >>= 1) sh += __shfl_xor(sh, k, 16);
    rd[h] = 1.f/(sh + 1e-16f);
  }

  // pass B: 4-deep gather pipeline
  float acc[4][8] = {};
  int nch = (end - beg + 15) >> 4;
  for (int c = 0; c < nch; ++c){
    int cs = beg + c*16;
    int cn = min(16, end - cs);
    if (ln < cn){
      int sj; f32x4 ev;
      if (c == 0){ sj = sj0; ev = ev0; }
      else if (c == 1){ sj = sj1; ev = ev1; }
      else {
        sj = csrc[cs + ln];
        f32x4 a4 = *(const f32x4*)(as1 + 4*sj);
        #pragma unroll
        for (int h = 0; h < 4; ++h)
          ev[h] = __expf(fminf(lrelu(a4[h] + ad4[h]), 60.f));
      }
      s_src[grp][ln] = (ushort)sj;
      #pragma unroll
      for (int h = 0; h < 4; ++h)
        s_w[grp][h][ln] = ev[h] * rd[h];
    }
    int e = 0;
    if (cn >= 4){
      uint4 u0 = *(const uint4*)(xb + (size_t)s_src[grp][0]*IN_CH + ln*8);
      uint4 u1 = *(const uint4*)(xb + (size_t)s_src[grp][1]*IN_CH + ln*8);
      uint4 u2 = *(const uint4*)(xb + (size_t)s_src[grp][2]*IN_CH + ln*8);
      uint4 u3 = *(const uint4*)(xb + (size_t)s_src[grp][3]*IN_CH + ln*8);
      for (; e + 7 < cn; e += 4){
        uint4 n0 = *(const uint4*)(xb + (size_t)s_src[grp][e+4]*IN_CH + ln*8);
        uint4 n1 = *(const uint4*)(xb + (size_t)s_src[grp][e+5]*IN_CH + ln*8);
        uint4 n2 = *(const uint4*)(xb + (size_t)s_src[grp][e+6]*IN_CH + ln*8);
        uint4 n3 = *(const uint4*)(xb + (size_t)s_src[grp][e+7]*IN_CH + ln*8);
        float v0[8], v1[8], v2[8], v3[8];
        unpack8(u0, v0); unpack8(u1, v1); unpack8(u2, v2); unpack8(u3, v3);
        #pragma unroll
        for (int h = 0; h < 4; ++h){
          float w0 = s_w[grp][h][e],   w1 = s_w[grp][h][e+1];
          float w2 = s_w[grp][h][e+2], w3 = s_w[grp][h][e+3];
          #pragma unroll
          for (int cc = 0; cc < 8; ++cc)
            acc[h][cc] += w0*v0[cc] + w1*v1[cc] + w2*v2[cc] + w3*v3[cc];
        }
        u0 = n0; u1 = n1; u2 = n2; u3 = n3;
      }
      {
        float v0[8], v1[8], v2[8], v3[8];
        unpack8(u0, v0); unpack8(u1, v1); unpack8(u2, v2); unpack8(u3, v3);
        #pragma unroll
        for (int h = 0; h < 4; ++h){
          float w0 = s_w[grp][h][e],   w1 = s_w[grp][h][e+1];
          float w2 = s_w[grp][h][e+2], w3 = s_w[grp][h][e+3];
          #pragma unroll
          for (int cc = 0; cc < 8; ++cc)
            acc[h][cc] += w0*v0[cc] + w1*v1[cc] + w2*v2[cc] + w3*v3[cc];
        }
        e += 4;
      }
    }
    for (; e < cn; ++e){
      uint4 u = *(const uint4*)(xb + (size_t)s_src[grp][e]*IN_CH + ln*8);
      float v[8];
      unpack8(u, v);
      #pragma unroll
      for (int h = 0; h < 4; ++h){
        float w = s_w[grp][h][e];
        #pragma unroll
        for (int cc = 0; cc < 8; ++cc) acc[h][cc] += w*v[cc];
      }
    }
  }
  #pragma unroll
  for (int h = 0; h < 4; ++h){
    uint4 o;
    o.x = (unsigned)f2b(acc[h][0]) | ((unsigned)f2b(acc[h][1])<<16);
    o.y = (unsigned)f2b(acc[h][2]) | ((unsigned)f2b(acc[h][3])<<16);
    o.z = (unsigned)f2b(acc[h][4]) | ((unsigned)f2b(acc[h][5])<<16);
    o.w = (unsigned)f2b(acc[h][6]) | ((unsigned)f2b(acc[h][7])<<16);
    *(uint4*)(xagg + (size_t)i*512 + h*128 + ln*8) = o;
  }
}

// ---------------- conv2 fused softmax+aggregate: 16 lanes/node, 4 nodes/block --
__global__ __launch_bounds__(64) void k_fagg2(
    const ushort* __restrict__ h2b, const float* __restrict__ as2,
    const float* __restrict__ ad2, const int* __restrict__ rowptr,
    const ushort* __restrict__ csrc, const float* __restrict__ bias,
    ushort* __restrict__ z2b, int n)
{
  __shared__ float  s_w[4][17];
  __shared__ ushort s_src[4][16];
  int tid = threadIdx.x;
  int grp = tid >> 4, ln = tid & 15;
  int i = blockIdx.x*4 + grp;
  if (i >= n) return;
  int beg = rowptr[i], end = rowptr[i+1];
  float adv = ad2[i];

  float S = 0.f;
  float ev0 = 0.f, ev1 = 0.f;
  int sj0 = 0, sj1 = 0, it = 0;
  for (int sl = beg + ln; sl < end; sl += 16, ++it){
    int sj = csrc[sl];
    float ev = __expf(fminf(lrelu(as2[sj] + adv), 60.f));
    if (it == 0){ ev0 = ev; sj0 = sj; }
    else if (it == 1){ ev1 = ev; sj1 = sj; }
    S += ev;
  }
  #pragma unroll
  for (int k = 8; k >= 1; k >>= 1) S += __shfl_xor(S, k, 16);
  float rd = 1.f/(S + 1e-16f);

  float acc[4] = {};
  int nch = (end - beg + 15) >> 4;
  for (int c = 0; c < nch; ++c){
    int cs = beg + c*16;
    int cn = min(16, end - cs);
    if (ln < cn){
      int sj; float ev;
      if (c == 0){ sj = sj0; ev = ev0; }
      else if (c == 1){ sj = sj1; ev = ev1; }
      else { sj = csrc[cs + ln]; ev = __expf(fminf(lrelu(as2[sj] + adv), 60.f)); }
      s_src[grp][ln] = (ushort)sj;
      s_w[grp][ln] = ev * rd;
    }
    int e = 0;
    if (cn >= 2){
      ushort4 uA = *(const ushort4*)(h2b + (size_t)s_src[grp][0]*OUT_CH + ln*4);
      ushort4 uB = *(const ushort4*)(h2b + (size_t)s_src[grp][1]*OUT_CH + ln*4);
      for (; e + 3 < cn; e += 2){
        ushort4 uC = *(const ushort4*)(h2b + (size_t)s_src[grp][e+2]*OUT_CH + ln*4);
        ushort4 uD = *(const ushort4*)(h2b + (size_t)s_src[grp][e+3]*OUT_CH + ln*4);
        float wA = s_w[grp][e], wB = s_w[grp][e+1];
        acc[0] += wA*b2f(uA.x) + wB*b2f(uB.x);
        acc[1] += wA*b2f(uA.y) + wB*b2f(uB.y);
        acc[2] += wA*b2f(uA.z) + wB*b2f(uB.z);
        acc[3] += wA*b2f(uA.w) + wB*b2f(uB.w);
        uA = uC; uB = uD;
      }
      {
        float wA = s_w[grp][e], wB = s_w[grp][e+1];
        acc[0] += wA*b2f(uA.x) + wB*b2f(uB.x);
        acc[1] += wA*b2f(uA.y) + wB*b2f(uB.y);
        acc[2] += wA*b2f(uA.z) + wB*b2f(uB.z);
        acc[3] += wA*b2f(uA.w) + wB*b2f(uB.w);
        e += 2;
      }
    }
    if (e < cn){
      int sj = s_src[grp][e];
      float w = s_w[grp][e];
      ushort4 u = *(const ushort4*)(h2b + (size_t)sj*OUT_CH + ln*4);
      acc[0] += w*b2f(u.x); acc[1] += w*b2f(u.y);
      acc[2] += w*b2f(u.z); acc[3] += w*b2f(u.w);
    }
  }
  ushort4 o;
  o.x = f2b(acc[0] + bias[ln*4]);
  o.y = f2b(acc[1] + bias[ln*4+1]);
  o.z = f2b(acc[2] + bias[ln*4+2]);
  o.w = f2b(acc[3] + bias[ln*4+3]);
  *(ushort4*)(z2b + (size_t)i*OUT_CH + ln*4) = o;
}

// ---------------- bf16 MFMA GEMM, BM=128, BN=64, BK=64, strided, batched-z ----
template<bool RELU_BIAS>
__global__ __launch_bounds__(256) void k_gemm2(
    const ushort* __restrict__ A, const ushort* __restrict__ Bt,
    ushort* __restrict__ Cb, const float* __restrict__ bias,
    int M, int K, int lda, int ldc, int aZ, int bZ, int cZ)
{
  constexpr int BM = 128, BN = 64, NF = 2;
  __shared__ uint4 As[BM*8];
  __shared__ uint4 Bs[BN*8];
  int tid = threadIdx.x;
  int wave = tid >> 6, lane = tid & 63;
  int wr = wave >> 1, wc = wave & 1;
  int bm = blockIdx.y * BM;
  int z = blockIdx.z;
  const ushort* Az = A + (size_t)z*aZ;
  const ushort* Bz = Bt + (size_t)z*bZ;
  int g = lane >> 4, lr = lane & 15;

  f32x4 acc[4][NF];
  #pragma unroll
  for (int m = 0; m < 4; ++m)
    #pragma unroll
    for (int n = 0; n < NF; ++n) acc[m][n] = (f32x4)(0.f);

  for (int k0 = 0; k0 < K; k0 += 64){
    for (int idx = tid; idx < BM*8; idx += 256){
      int r = idx >> 3, c = idx & 7;
      int gr = bm + r;
      uint4 v = make_uint4(0u,0u,0u,0u);
      if (gr < M) v = *(const uint4*)(Az + (size_t)gr*lda + k0 + c*8);
      As[r*8 + (c ^ (r & 7))] = v;
    }
    for (int idx = tid; idx < BN*8; idx += 256){
      int r = idx >> 3, c = idx & 7;
      uint4 v = *(const uint4*)(Bz + (size_t)r*K + k0 + c*8);
      Bs[r*8 + (c ^ (r & 7))] = v;
    }
    __syncthreads();
    #pragma unroll
    for (int kk = 0; kk < 2; ++kk){
      short8v af[4], bf[NF];
      #pragma unroll
      for (int m = 0; m < 4; ++m){
        int r = wr*64 + m*16 + lr;
        int c = kk*4 + g;
        af[m] = *(const short8v*)&As[r*8 + (c ^ (r & 7))];
      }
      #pragma unroll
      for (int n = 0; n < NF; ++n){
        int r = wc*32 + n*16 + lr;
        int c = kk*4 + g;
        bf[n] = *(const short8v*)&Bs[r*8 + (c ^ (r & 7))];
      }
      #pragma unroll
      for (int m = 0; m < 4; ++m)
        #pragma unroll
        for (int n = 0; n < NF; ++n)
          acc[m][n] = __builtin_amdgcn_mfma_f32_16x16x32_bf16(af[m], bf[n], acc[m][n], 0, 0, 0);
    }
    __syncthreads();
  }
  #pragma unroll
  for (int m = 0; m < 4; ++m){
    #pragma unroll
    for (int q = 0; q < 4; ++q){
      int row = bm + wr*64 + m*16 + g*4 + q;
      if (row < M){
        #pragma unroll
        for (int n = 0; n < NF; ++n){
          int col = wc*32 + n*16 + lr;
          float v = acc[m][n][q];
          if (RELU_BIAS) v = fmaxf(v + bias[cZ*z + col], 0.f);
          Cb[(size_t)row*ldc + cZ*z + col] = f2b(v);
        }
      }
    }
  }
}

// ---------------- decoder: 4 edges per 8-lane group (pos/neg x k, k+E/2) ------
__global__ void k_decode(const ushort* __restrict__ z2b, const int* __restrict__ pos,
                         const int* __restrict__ neg, float* __restrict__ out, int e){
  int g = blockIdx.x*256 + threadIdx.x;
  int hf = e >> 1;
  int k = g >> 3;
  int sub = g & 7;
  if (k >= hf) return;
  int a0 = __builtin_nontemporal_load(pos + k);
  int b0 = __builtin_nontemporal_load(pos + e + k);
  int a1 = __builtin_nontemporal_load(pos + k + hf);
  int b1 = __builtin_nontemporal_load(pos + e + k + hf);
  int a2 = __builtin_nontemporal_load(neg + k);
  int b2 = __builtin_nontemporal_load(neg + e + k);
  int a3 = __builtin_nontemporal_load(neg + k + hf);
  int b3 = __builtin_nontemporal_load(neg + e + k + hf);
  uint4 ua0 = *(const uint4*)(z2b + (size_t)a0*OUT_CH + sub*8);
  uint4 ub0 = *(const uint4*)(z2b + (size_t)b0*OUT_CH + sub*8);
  uint4 ua1 = *(const uint4*)(z2b + (size_t)a1*OUT_CH + sub*8);
  uint4 ub1 = *(const uint4*)(z2b + (size_t)b1*OUT_CH + sub*8);
  uint4 ua2 = *(const uint4*)(z2b + (size_t)a2*OUT_CH + sub*8);
  uint4 ub2 = *(const uint4*)(z2b + (size_t)b2*OUT_CH + sub*8);
  uint4 ua3 = *(const uint4*)(z2b + (size_t)a3*OUT_CH + sub*8);
  uint4 ub3 = *(const uint4*)(z2b + (size_t)b3*OUT_CH + sub*8);
  float p0 = dot2(ua0.x, ub0.x) + dot2(ua0.y, ub0.y) + dot2(ua0.z, ub0.z) + dot2(ua0.w, ub0.w);
  float p1 = dot2(ua1.x, ub1.x) + dot2(ua1.y, ub1.y) + dot2(ua1.z, ub1.z) + dot2(ua1.w, ub1.w);
  float p2 = dot2(ua2.x, ub2.x) + dot2(ua2.y, ub2.y) + dot2(ua2.z, ub2.z) + dot2(ua2.w, ub2.w);
  float p3 = dot2(ua3.x, ub3.x) + dot2(ua3.y, ub3.y) + dot2(ua3.z, ub3.z) + dot2(ua3.w, ub3.w);
  #pragma unroll
  for (int mm = 4; mm >= 1; mm >>= 1){
    p0 += __shfl_xor(p0, mm, 64);
    p1 += __shfl_xor(p1, mm, 64);
    p2 += __shfl_xor(p2, mm, 64);
    p3 += __shfl_xor(p3, mm, 64);
  }
  if (sub == 0){
    __builtin_nontemporal_store(p0, out + k);
    __builtin_nontemporal_store(p1, out + k + hf);
    __builtin_nontemporal_store(p2, out + e + k);
    __builtin_nontemporal_store(p3, out + e + k + hf);
  }
}

extern "C" void kernel_launch(void* const* d_in, const int* in_sizes, int n_in,
                              void* d_out, int out_size, void* d_ws, size_t ws_size,
                              hipStream_t stream) {
  const float* x        = (const float*)d_in[0];
  const int*   pos      = (const int*)d_in[1];
  const int*   neg      = (const int*)d_in[2];
  const float* W1       = (const float*)d_in[3];
  const float* att_src1 = (const float*)d_in[4];
  const float* att_dst1 = (const float*)d_in[5];
  const float* b1       = (const float*)d_in[6];
  const float* W2       = (const float*)d_in[7];
  const float* att_src2 = (const float*)d_in[8];
  const float* att_dst2 = (const float*)d_in[9];
  const float* b2       = (const float*)d_in[10];
  float* out = (float*)d_out;

  const int N = in_sizes[0] / IN_CH;   // 50000
  const int E = in_sizes[1] / 2;       // 800000
  const int NNZ = E + N;               // edges + self-loops
  const int NQ4 = (N + NQ - 1) / NQ;   // 12500 (<= MAXNQ)

  char* w = (char*)d_ws;
  ushort* xb   = (ushort*)w;  w += (size_t)N*IN_CH*2;
  ushort* xagg = (ushort*)w;  w += (size_t)N*512*2;          // 51.2MB; sub-reused below
  ushort* z1b  = (ushort*)w;  w += (size_t)N*C1*2;
  float* as1   = (float*)w;   w += (size_t)N*4*4;
  float* ad1   = (float*)w;   w += (size_t)N*4*4;
  float* as2   = (float*)w;   w += (size_t)N*4;
  float* ad2   = (float*)w;   w += (size_t)N*4;
  ushort* W1t  = (ushort*)w;  w += (size_t)C1*IN_CH*2;
  ushort* W2t  = (ushort*)w;  w += (size_t)OUT_CH*C1*2;
  float* was4  = (float*)w;   w += 512*4;
  float* wad4  = (float*)w;   w += 512*4;
  float* w2s   = (float*)w;   w += 256*4;
  float* w2d   = (float*)w;   w += 256*4;
  int* deg     = (int*)w;     w += (size_t)N*4;
  int* rowptr  = (int*)w;     w += (size_t)(N+1)*4;
  int* bsum    = (int*)w;     w += (size_t)256*4;
  unsigned* part = (unsigned*)w; w += (size_t)NQ*NSL*NQ4*4;  // 12.8MB
  ushort* csrc = (ushort*)w;  w += (size_t)NNZ*2;

  // sub-allocations inside xagg (region dead after z1 GEMM):
  ushort* h2b = xagg;                                  // 6.4MB
  ushort* z2b = xagg + (size_t)N*OUT_CH;               // 6.4MB

  int nb = (N + 255)/256;
  const int* pdst = pos + E;

  k_setup<<<194, 256, 0, stream>>>(W1, W1t, W2, W2t,
      att_src1, att_dst1, att_src2, att_dst2, was4, wad4, w2s, w2d);
  k_hist2<<<NQ*NSL, 1024, 0, stream>>>(pdst, part, E, NQ4, N);
  k_degred<<<nb, 256, 0, stream>>>(part, deg, bsum, N, NQ4);
  k_fattc<<<(N + 3)/4, 256, 0, stream>>>(x, was4, wad4, xb, as1, ad1, N);
  k_scanfinal<<<nb, 256, 0, stream>>>(deg, bsum, rowptr, csrc, N);
  k_scatter2<<<NQ*NSL, 1024, 0, stream>>>(pos, pdst, rowptr, part, csrc, E, NQ4, N);

  k_fagg1<<<(N + 3)/4, 64, 0, stream>>>(xb, as1, ad1, rowptr, csrc, xagg, N);

  {  // z1 = relu(blockdiag(xagg_h @ W1_h) + b1), 4 heads via blockIdx.z
    dim3 g(1, (N + 127)/128, 4);
    k_gemm2<true><<<g, 256, 0, stream>>>(xagg, W1t, z1b, b1,
        N, IN_CH, 512, C1, IN_CH, OUT_CH*IN_CH, OUT_CH);
  }
  k_fatt2<<<(N + 3)/4, 256, 0, stream>>>(z1b, w2s, w2d, as2, ad2, N);

  {  // h2 = z1 @ W2
    dim3 g(1, (N + 127)/128, 1);
    k_gemm2<false><<<g, 256, 0, stream>>>(z1b, W2t, h2b, nullptr,
        N, C1, C1, OUT_CH, 0, 0, 0);
  }
  k_fagg2<<<(N + 3)/4, 64, 0, stream>>>(h2b, as2, ad2, rowptr, csrc, b2, z2b, N);

  int db = (int)(((size_t)(E/2)*8 + 255)/256);
  k_decode<<<db, 256, 0, stream>>>(z2b, pos, neg, out, E);
}